// Round 1
// baseline (525.297 us; speedup 1.0000x reference)
//
#include <hip/hip_runtime.h>

// ---------- types ----------
typedef short short8 __attribute__((ext_vector_type(8)));   // 8 bf16 as i16
typedef float f32x4 __attribute__((ext_vector_type(4)));

#define GLOBAL_AS __attribute__((address_space(1)))
#define LDS_AS    __attribute__((address_space(3)))

__device__ __forceinline__ unsigned short f2bf(float f) {
    unsigned u = __builtin_bit_cast(unsigned, f);
    u += 0x7fffu + ((u >> 16) & 1u);          // round-to-nearest-even
    return (unsigned short)(u >> 16);
}

// ---------- convert kernels (memory-bound, vectorized) ----------
// codebook gather: int32 idx -> bf16 value
__global__ __launch_bounds__(256) void k_idx2bf(const int* __restrict__ idx,
                                                const float* __restrict__ cb,
                                                ushort* __restrict__ out, int n4) {
    int i = blockIdx.x * 256 + threadIdx.x;
    if (i >= n4) return;
    int4 v = reinterpret_cast<const int4*>(idx)[i];
    ushort4 o;
    o.x = f2bf(cb[v.x]); o.y = f2bf(cb[v.y]);
    o.z = f2bf(cb[v.z]); o.w = f2bf(cb[v.w]);
    reinterpret_cast<ushort4*>(out)[i] = o;
}

// fp32 -> bf16
__global__ __launch_bounds__(256) void k_f2bf(const float* __restrict__ in,
                                              ushort* __restrict__ out, int n4) {
    int i = blockIdx.x * 256 + threadIdx.x;
    if (i >= n4) return;
    float4 v = reinterpret_cast<const float4*>(in)[i];
    ushort4 o;
    o.x = f2bf(v.x); o.y = f2bf(v.y); o.z = f2bf(v.z); o.w = f2bf(v.w);
    reinterpret_cast<ushort4*>(out)[i] = o;
}

// ---------- bf16 gemm_bt (m97 structure): C[M,N] = A[M,K] * B[N,K]^T ----------
// BM=BN=128, BK=64, 256 threads = 4 waves (2x2), each wave 64x64 out,
// 16x16x32 MFMA, global_load_lds width 16, 2 barriers per K-tile.
// EPI=0: C=bf16, val = acc * extra[row]   (dequant: scale per output row)
// EPI=1: C=f32,  val = acc + extra[col]   (linear: bias per output col)
template <int EPI>
__global__ __launch_bounds__(256, 2) void gemm_bt(const ushort* __restrict__ A,
                                                  const ushort* __restrict__ B,
                                                  void* __restrict__ C,
                                                  const float* __restrict__ extra) {
    constexpr int BM = 128, BN = 128, BK = 64;
    constexpr int K = 4096, N = 4096;

    __shared__ ushort sA[BM * BK];
    __shared__ ushort sB[BN * BK];

    const int tid  = threadIdx.x;
    const int w    = tid >> 6;
    const int lane = tid & 63;
    const int m0 = blockIdx.y * BM;
    const int n0 = blockIdx.x * BN;

    // staging geometry: each global_load_lds call = one wave = 1024B = 8 rows of 64 bf16
    const int srow = lane >> 3;          // row within the 8-row chunk
    const int scol = (lane & 7) * 8;     // bf16 col of this lane's 16B
    const ushort* gA = A + (size_t)(m0 + srow) * K + scol;
    const ushort* gB = B + (size_t)(n0 + srow) * K + scol;

    // fragment geometry (A and B operands share the layout: row=lane&15, k=(lane>>4)*8)
    const int fr = lane & 15;
    const int fk = (lane >> 4) * 8;
    const int wr = (w >> 1) * 64;        // wave row offset in tile
    const int wc = (w & 1) * 64;         // wave col offset in tile

    f32x4 zero = {0.f, 0.f, 0.f, 0.f};
    f32x4 acc[4][4];
#pragma unroll
    for (int i = 0; i < 4; ++i)
#pragma unroll
        for (int j = 0; j < 4; ++j) acc[i][j] = zero;

    for (int kt = 0; kt < K / BK; ++kt) {
        const int kb = kt * BK;
        // ---- stage A,B tiles (8 x global_load_lds_dwordx4 per thread-wave set) ----
#pragma unroll
        for (int i = 0; i < 4; ++i) {
            const int row0 = i * 32 + w * 8;  // wave-uniform
            __builtin_amdgcn_global_load_lds(
                (const GLOBAL_AS void*)(gA + (size_t)row0 * K + kb),
                (LDS_AS void*)(sA + row0 * BK), 16, 0, 0);
            __builtin_amdgcn_global_load_lds(
                (const GLOBAL_AS void*)(gB + (size_t)row0 * K + kb),
                (LDS_AS void*)(sB + row0 * BK), 16, 0, 0);
        }
        __syncthreads();   // compiler drains vmcnt before barrier

        // ---- compute: 2 k-steps x 16 MFMA per wave ----
#pragma unroll
        for (int kk = 0; kk < BK; kk += 32) {
            short8 af[4], bfr[4];
#pragma unroll
            for (int mi = 0; mi < 4; ++mi)
                af[mi] = *reinterpret_cast<const short8*>(sA + (wr + mi * 16 + fr) * BK + kk + fk);
#pragma unroll
            for (int ni = 0; ni < 4; ++ni)
                bfr[ni] = *reinterpret_cast<const short8*>(sB + (wc + ni * 16 + fr) * BK + kk + fk);
#pragma unroll
            for (int mi = 0; mi < 4; ++mi)
#pragma unroll
                for (int ni = 0; ni < 4; ++ni)
                    acc[mi][ni] = __builtin_amdgcn_mfma_f32_16x16x32_bf16(
                        af[mi], bfr[ni], acc[mi][ni], 0, 0, 0);
        }
        __syncthreads();
    }

    // ---- epilogue: C/D layout col=lane&15, row=(lane>>4)*4+reg ----
    const int rbase = m0 + wr + ((lane >> 4) * 4);
    const int cbase = n0 + wc + (lane & 15);
    if (EPI == 0) {
        ushort* Cw = (ushort*)C;
#pragma unroll
        for (int mi = 0; mi < 4; ++mi) {
#pragma unroll
            for (int r = 0; r < 4; ++r) {
                const int row = rbase + mi * 16 + r;
                const float s = extra[row];
#pragma unroll
                for (int ni = 0; ni < 4; ++ni) {
                    const int col = cbase + ni * 16;
                    Cw[(size_t)row * N + col] = f2bf(acc[mi][ni][r] * s);
                }
            }
        }
    } else {
        float* Cf = (float*)C;
#pragma unroll
        for (int ni = 0; ni < 4; ++ni) {
            const int col = cbase + ni * 16;
            const float b = extra[col];
#pragma unroll
            for (int mi = 0; mi < 4; ++mi) {
#pragma unroll
                for (int r = 0; r < 4; ++r) {
                    const int row = rbase + mi * 16 + r;
                    Cf[(size_t)row * N + col] = acc[mi][ni][r] + b;
                }
            }
        }
    }
}

// ---------- launch ----------
extern "C" void kernel_launch(void* const* d_in, const int* in_sizes, int n_in,
                              void* d_out, int out_size, void* d_ws, size_t ws_size,
                              hipStream_t stream) {
    const float* x     = (const float*)d_in[0];   // (4,2048,4096) f32
    const int*   widx  = (const int*)  d_in[1];   // (4096,4096) i32
    const float* wscal = (const float*)d_in[2];   // (4096,)
    const float* bias  = (const float*)d_in[3];   // (4096,)
    const float* rot   = (const float*)d_in[4];   // (4096,4096) f32
    const float* cb    = (const float*)d_in[5];   // (16,)
    float* out = (float*)d_out;                   // (4,2048,4096) f32

    constexpr size_t IN_F = 4096, OUT_F = 4096, MTOK = 8192;  // 4*2048
    char* ws = (char*)d_ws;
    ushort* wq = (ushort*)(ws);                                  // 32 MiB: codebook[idx] bf16
    ushort* rb = (ushort*)(ws + 33554432);                       // 32 MiB: rotation bf16
    ushort* xb = (ushort*)(ws + 67108864);                       // 64 MiB: x bf16
    ushort* wb = (ushort*)(ws + 134217728);                      // 32 MiB: dequantized W bf16
    (void)ws_size; (void)in_sizes; (void)n_in; (void)out_size;   // total 160 MiB

    // converts (memory-bound)
    {
        int n4 = (int)(OUT_F * IN_F / 4);                        // 4,194,304
        k_idx2bf<<<n4 / 256, 256, 0, stream>>>(widx, cb, wq, n4);
        k_f2bf<<<n4 / 256, 256, 0, stream>>>(rot, rb, n4);
        int n4x = (int)(MTOK * IN_F / 4);                        // 8,388,608
        k_f2bf<<<n4x / 256, 256, 0, stream>>>(x, xb, n4x);
    }

    // GEMM A: W[o,j] = scale[o] * sum_i Wq[o,i] R[j,i]   (M=4096, N=4096)
    gemm_bt<0><<<dim3(4096 / 128, 4096 / 128), 256, 0, stream>>>(wq, rb, (void*)wb, wscal);

    // GEMM B: out[m,o] = sum_j x[m,j] W[o,j] + bias[o]   (M=8192, N=4096)
    gemm_bt<1><<<dim3(4096 / 128, 8192 / 128), 256, 0, stream>>>(xb, wb, (void*)out, bias);
}